// Round 1
// baseline (956.991 us; speedup 1.0000x reference)
//
#include <hip/hip_runtime.h>

#define NB    2
#define LX    2048
#define LZ    2048
#define HH    16
#define DA    64
#define DM    64
#define HD    1024        // H * DA = H * DM
#define SCALE 0.125f      // 1/sqrt(64)
#define MINF  -1000000.0f

// ---------------------------------------------------------------------------
// C[M,N] = A[M,K] @ W[K,N] (+ bias), fp32 row-major. M,N mult of 64, K mult 16.
// 64x64 block tile, BK=16, 256 threads, 4x4 micro-tile per thread.
// ---------------------------------------------------------------------------
__global__ __launch_bounds__(256) void gemm_nn_f32(
    const float* __restrict__ A, const float* __restrict__ W,
    const float* __restrict__ bias, float* __restrict__ C,
    int M, int N, int K)
{
    __shared__ float As[16][68];   // [k][m]  (transposed store, pad 68 for banks+align)
    __shared__ float Bs[16][68];   // [k][n]

    const int t  = threadIdx.x;
    const int n0 = blockIdx.x * 64;
    const int m0 = blockIdx.y * 64;
    const int tx = t & 15;         // col group
    const int ty = t >> 4;         // row group
    // staging indices
    const int ar = t >> 2;         // 0..63  A row
    const int ak = (t & 3) * 4;    // 0..12  A k (float4)
    const int bk = t >> 4;         // 0..15  W k
    const int bn = (t & 15) * 4;   // 0..60  W col (float4)

    float acc[4][4] = {{0.f, 0.f, 0.f, 0.f}, {0.f, 0.f, 0.f, 0.f},
                       {0.f, 0.f, 0.f, 0.f}, {0.f, 0.f, 0.f, 0.f}};

    for (int k0 = 0; k0 < K; k0 += 16) {
        float4 av = *(const float4*)&A[(size_t)(m0 + ar) * K + k0 + ak];
        float4 bv = *(const float4*)&W[(size_t)(k0 + bk) * N + n0 + bn];
        __syncthreads();                       // previous iteration's reads done
        As[ak + 0][ar] = av.x;
        As[ak + 1][ar] = av.y;
        As[ak + 2][ar] = av.z;
        As[ak + 3][ar] = av.w;
        *(float4*)&Bs[bk][bn] = bv;
        __syncthreads();
        #pragma unroll
        for (int k = 0; k < 16; ++k) {
            float4 a4 = *(const float4*)&As[k][ty * 4];
            float4 b4 = *(const float4*)&Bs[k][tx * 4];
            float a[4] = {a4.x, a4.y, a4.z, a4.w};
            float bb[4] = {b4.x, b4.y, b4.z, b4.w};
            #pragma unroll
            for (int i = 0; i < 4; ++i)
                #pragma unroll
                for (int j = 0; j < 4; ++j)
                    acc[i][j] += a[i] * bb[j];
        }
    }

    #pragma unroll
    for (int i = 0; i < 4; ++i) {
        float4 r = make_float4(acc[i][0], acc[i][1], acc[i][2], acc[i][3]);
        if (bias) {
            r.x += bias[n0 + tx * 4 + 0];
            r.y += bias[n0 + tx * 4 + 1];
            r.z += bias[n0 + tx * 4 + 2];
            r.w += bias[n0 + tx * 4 + 3];
        }
        *(float4*)&C[(size_t)(m0 + ty * 4 + i) * N + n0 + tx * 4] = r;
    }
}

// ---------------------------------------------------------------------------
// Classify each 64x64 tile of combined mask (attention_mask * padding_mask):
// 0 = all masked out, 1 = all pass, 2 = mixed. One block per (b, xb, zb).
// ---------------------------------------------------------------------------
__global__ __launch_bounds__(256) void mask_classify(
    const int* __restrict__ amask, const int* __restrict__ pmask,
    int* __restrict__ cls)
{
    const int bid = blockIdx.x;               // b*1024 + xb*32 + zb
    const int b  = bid >> 10;
    const int xb = (bid >> 5) & 31;
    const int zb = bid & 31;
    const int t  = threadIdx.x;

    int andv = 1, orv = 0;
    #pragma unroll
    for (int i = 0; i < 16; ++i) {
        int e = t + i * 256;                  // 0..4095 over 64x64 tile
        int r = e >> 6, z = e & 63;
        int m = amask[((size_t)b * LX + xb * 64 + r) * LZ + zb * 64 + z];
        int p = pmask[(size_t)b * LZ + zb * 64 + z];
        int v = (m != 0) & (p != 0);
        andv &= v;
        orv  |= v;
    }
    __shared__ int sa[256];
    __shared__ int so[256];
    sa[t] = andv; so[t] = orv;
    __syncthreads();
    for (int s = 128; s > 0; s >>= 1) {
        if (t < s) { sa[t] &= sa[t + s]; so[t] |= so[t + s]; }
        __syncthreads();
    }
    if (t == 0) cls[bid] = so[0] ? (sa[0] ? 1 : 2) : 0;
}

// ---------------------------------------------------------------------------
// Flash attention, fp32. One block per (qb, h, b); 64 q-rows x 64 kv per tile.
// Thread owns rows {rr, rr+32} and 8 contiguous columns (cg*8..cg*8+7).
// Kt buffer is reused to hold P after S-phase (saves LDS -> 3 blocks/CU).
// ---------------------------------------------------------------------------
__global__ __launch_bounds__(256) void attn_f32(
    const float* __restrict__ Qg, const float* __restrict__ Kg,
    const float* __restrict__ Vg, const int* __restrict__ amask,
    const int* __restrict__ pmask, const int* __restrict__ cls,
    float* __restrict__ O)
{
    __shared__ float Qs[64][68];   // [row][d]
    __shared__ float Kt[64][68];   // [d][z] during S, then [row][z] as P
    __shared__ float Vs[64][68];   // [z][m]

    const int qb = blockIdx.x, h = blockIdx.y, b = blockIdx.z;
    const int t  = threadIdx.x;
    const int rr = t >> 3;         // 0..31 -> rows rr, rr+32
    const int cg = t & 7;          // 8 cols: cg*8 .. cg*8+7
    const int x0 = qb * 64;

    // ---- load Q tile ----
    const size_t qbase = ((size_t)b * LX + x0) * HD + h * DA;
    #pragma unroll
    for (int i = 0; i < 4; ++i) {
        int e = t + i * 256;
        int r = e >> 4, d4 = (e & 15) * 4;
        *(float4*)&Qs[r][d4] = *(const float4*)&Qg[qbase + (size_t)r * HD + d4];
    }

    float m0r = -INFINITY, m1r = -INFINITY;
    float l0 = 0.f, l1 = 0.f;
    float o0[8] = {0,0,0,0,0,0,0,0};
    float o1[8] = {0,0,0,0,0,0,0,0};

    for (int zb = 0; zb < LZ / 64; ++zb) {
        const int cl = cls[(size_t)b * 1024 + qb * 32 + zb];
        if (cl == 0) continue;                 // uniform across block

        // ---- stage K (transposed) and V ----
        __syncthreads();                       // prior reads of Kt/Vs complete
        {
            const size_t kb = ((size_t)b * LZ + zb * 64) * HD + h * DA;
            const size_t vb = ((size_t)b * LZ + zb * 64) * HD + h * DM;
            #pragma unroll
            for (int i = 0; i < 4; ++i) {
                int e = t + i * 256;
                int z = e >> 4, d4 = (e & 15) * 4;
                float4 kv = *(const float4*)&Kg[kb + (size_t)z * HD + d4];
                float4 vv = *(const float4*)&Vg[vb + (size_t)z * HD + d4];
                Kt[d4 + 0][z] = kv.x;
                Kt[d4 + 1][z] = kv.y;
                Kt[d4 + 2][z] = kv.z;
                Kt[d4 + 3][z] = kv.w;
                *(float4*)&Vs[z][d4] = vv;
            }
        }
        __syncthreads();

        // ---- S = Q @ K^T ----
        float s0[8] = {0,0,0,0,0,0,0,0};
        float s1[8] = {0,0,0,0,0,0,0,0};
        #pragma unroll 8
        for (int d = 0; d < 64; ++d) {
            float q0 = Qs[rr][d];
            float q1 = Qs[rr + 32][d];
            float4 ka = *(const float4*)&Kt[d][cg * 8];
            float4 kb4 = *(const float4*)&Kt[d][cg * 8 + 4];
            s0[0] += q0 * ka.x;  s0[1] += q0 * ka.y;  s0[2] += q0 * ka.z;  s0[3] += q0 * ka.w;
            s0[4] += q0 * kb4.x; s0[5] += q0 * kb4.y; s0[6] += q0 * kb4.z; s0[7] += q0 * kb4.w;
            s1[0] += q1 * ka.x;  s1[1] += q1 * ka.y;  s1[2] += q1 * ka.z;  s1[3] += q1 * ka.w;
            s1[4] += q1 * kb4.x; s1[5] += q1 * kb4.y; s1[6] += q1 * kb4.z; s1[7] += q1 * kb4.w;
        }

        // ---- scale + mask ----
        if (cl == 2) {
            const int* am0 = &amask[((size_t)b * LX + x0 + rr) * LZ + zb * 64 + cg * 8];
            const int* am1 = am0 + (size_t)32 * LZ;
            const int* pm  = &pmask[(size_t)b * LZ + zb * 64 + cg * 8];
            #pragma unroll
            for (int j = 0; j < 8; ++j) {
                int p = (pm[j] != 0);
                s0[j] = ((am0[j] != 0) & p) ? s0[j] * SCALE : MINF;
                s1[j] = ((am1[j] != 0) & p) ? s1[j] * SCALE : MINF;
            }
        } else {
            #pragma unroll
            for (int j = 0; j < 8; ++j) { s0[j] *= SCALE; s1[j] *= SCALE; }
        }

        // ---- online softmax (row split across 8 lanes) ----
        float mx0 = s0[0], mx1 = s1[0];
        #pragma unroll
        for (int j = 1; j < 8; ++j) { mx0 = fmaxf(mx0, s0[j]); mx1 = fmaxf(mx1, s1[j]); }
        mx0 = fmaxf(mx0, __shfl_xor(mx0, 1));
        mx0 = fmaxf(mx0, __shfl_xor(mx0, 2));
        mx0 = fmaxf(mx0, __shfl_xor(mx0, 4));
        mx1 = fmaxf(mx1, __shfl_xor(mx1, 1));
        mx1 = fmaxf(mx1, __shfl_xor(mx1, 2));
        mx1 = fmaxf(mx1, __shfl_xor(mx1, 4));

        const float mn0 = fmaxf(m0r, mx0);
        const float mn1 = fmaxf(m1r, mx1);
        const float al0 = __expf(m0r - mn0);   // first tile: exp(-inf)=0
        const float al1 = __expf(m1r - mn1);
        float sum0 = 0.f, sum1 = 0.f;
        #pragma unroll
        for (int j = 0; j < 8; ++j) {
            s0[j] = __expf(s0[j] - mn0); sum0 += s0[j];
            s1[j] = __expf(s1[j] - mn1); sum1 += s1[j];
        }
        sum0 += __shfl_xor(sum0, 1); sum0 += __shfl_xor(sum0, 2); sum0 += __shfl_xor(sum0, 4);
        sum1 += __shfl_xor(sum1, 1); sum1 += __shfl_xor(sum1, 2); sum1 += __shfl_xor(sum1, 4);
        l0 = l0 * al0 + sum0;  m0r = mn0;
        l1 = l1 * al1 + sum1;  m1r = mn1;
        #pragma unroll
        for (int j = 0; j < 8; ++j) { o0[j] *= al0; o1[j] *= al1; }

        // ---- write P into Kt buffer (reuse) ----
        __syncthreads();                       // everyone done reading Kt as K^T
        #pragma unroll
        for (int j = 0; j < 8; ++j) {
            Kt[rr][cg * 8 + j]      = s0[j];
            Kt[rr + 32][cg * 8 + j] = s1[j];
        }
        __syncthreads();

        // ---- O += P @ V ----
        #pragma unroll 8
        for (int z = 0; z < 64; ++z) {
            float p0 = Kt[rr][z];
            float p1 = Kt[rr + 32][z];
            float4 va = *(const float4*)&Vs[z][cg * 8];
            float4 vb4 = *(const float4*)&Vs[z][cg * 8 + 4];
            o0[0] += p0 * va.x;  o0[1] += p0 * va.y;  o0[2] += p0 * va.z;  o0[3] += p0 * va.w;
            o0[4] += p0 * vb4.x; o0[5] += p0 * vb4.y; o0[6] += p0 * vb4.z; o0[7] += p0 * vb4.w;
            o1[0] += p1 * va.x;  o1[1] += p1 * va.y;  o1[2] += p1 * va.z;  o1[3] += p1 * va.w;
            o1[4] += p1 * vb4.x; o1[5] += p1 * vb4.y; o1[6] += p1 * vb4.z; o1[7] += p1 * vb4.w;
        }
    }

    // ---- normalize + store (layout: [b, x, h*DM + m]) ----
    const float il0 = 1.f / l0;
    const float il1 = 1.f / l1;
    const size_t ob0 = ((size_t)b * LX + x0 + rr) * HD + h * DM + cg * 8;
    const size_t ob1 = ob0 + (size_t)32 * HD;
    *(float4*)&O[ob0]     = make_float4(o0[0]*il0, o0[1]*il0, o0[2]*il0, o0[3]*il0);
    *(float4*)&O[ob0 + 4] = make_float4(o0[4]*il0, o0[5]*il0, o0[6]*il0, o0[7]*il0);
    *(float4*)&O[ob1]     = make_float4(o1[0]*il1, o1[1]*il1, o1[2]*il1, o1[3]*il1);
    *(float4*)&O[ob1 + 4] = make_float4(o1[4]*il1, o1[5]*il1, o1[6]*il1, o1[7]*il1);
}

// ---------------------------------------------------------------------------
extern "C" void kernel_launch(void* const* d_in, const int* in_sizes, int n_in,
                              void* d_out, int out_size, void* d_ws, size_t ws_size,
                              hipStream_t stream)
{
    const float* primary = (const float*)d_in[0];
    const float* context = (const float*)d_in[1];
    const int*   pmask   = (const int*)d_in[2];
    const int*   amask   = (const int*)d_in[3];
    const float* Wq      = (const float*)d_in[4];
    const float* Wk      = (const float*)d_in[5];
    const float* Wv      = (const float*)d_in[6];
    const float* Wo      = (const float*)d_in[7];
    const float* bo      = (const float*)d_in[8];
    float* out = (float*)d_out;

    float* ws = (float*)d_ws;
    float* Q  = ws;                       // 4096x1024
    float* K  = ws + 4194304;             // 4096x1024
    float* V  = ws + 8388608;             // 4096x1024
    float* AO = ws + 12582912;            // 4096x1024
    int*   cls = (int*)(ws + 16777216);   // 2*32*32

    const int M = NB * LX;                // 4096
    dim3 gg(HD / 64, M / 64, 1);          // (16, 64)

    gemm_nn_f32<<<gg, 256, 0, stream>>>(primary, Wq, nullptr, Q, M, HD, 1024);
    gemm_nn_f32<<<gg, 256, 0, stream>>>(context, Wk, nullptr, K, M, HD, 1024);
    gemm_nn_f32<<<gg, 256, 0, stream>>>(context, Wv, nullptr, V, M, HD, 1024);
    mask_classify<<<NB * 32 * 32, 256, 0, stream>>>(amask, pmask, cls);
    attn_f32<<<dim3(LX / 64, HH, NB), 256, 0, stream>>>(Q, K, V, amask, pmask, cls, AO);
    gemm_nn_f32<<<gg, 256, 0, stream>>>(AO, Wo, bo, out, M, HD, 1024);
}

// Round 2
// 265.902 us; speedup vs baseline: 3.5990x; 3.5990x over previous
//
#include <hip/hip_runtime.h>

#define NB 2
#define LX 2048
#define LZ 2048
#define HH 16
#define DA 64
#define DM 64
#define HD 1024
#define SCALE 0.125f
#define MINF  -1000000.0f

typedef __attribute__((ext_vector_type(8))) short short8;
typedef __attribute__((ext_vector_type(4))) float f32x4;

static __device__ __forceinline__ ushort f2bf(float f) {
    union { float f; uint32_t u; } c; c.f = f;
    return (ushort)((c.u + 0x7FFFu + ((c.u >> 16) & 1u)) >> 16);
}

#define GL16(g, l) __builtin_amdgcn_global_load_lds( \
    (const __attribute__((address_space(1))) void*)(g), \
    (__attribute__((address_space(3))) void*)(l), 16, 0, 0)

// ---------------------------------------------------------------------------
// fp32 -> bf16 elementwise (activations). n4 = n/4.
// ---------------------------------------------------------------------------
__global__ __launch_bounds__(256) void f32_to_bf16_k(
    const float* __restrict__ in, ushort* __restrict__ out, int n4)
{
    int i = blockIdx.x * 256 + threadIdx.x;
    if (i >= n4) return;
    float4 v = ((const float4*)in)[i];
    ushort4 o;
    o.x = f2bf(v.x); o.y = f2bf(v.y); o.z = f2bf(v.z); o.w = f2bf(v.w);
    ((ushort4*)out)[i] = o;
}

// ---------------------------------------------------------------------------
// W[K][N] fp32 -> Wt[N][K] bf16 (64x64 LDS tile transpose).
// ---------------------------------------------------------------------------
__global__ __launch_bounds__(256) void wtrans_k(
    const float* __restrict__ W, ushort* __restrict__ Wt, int Kd, int Nd)
{
    __shared__ ushort Ls[64][72];
    const int n0 = blockIdx.x * 64, k0 = blockIdx.y * 64;
    const int t = threadIdx.x;
    const int rr = t >> 4, c4 = (t & 15) * 4;
    #pragma unroll
    for (int i = 0; i < 4; ++i) {
        int r = rr + i * 16;
        float4 v = *(const float4*)&W[(size_t)(k0 + r) * Nd + n0 + c4];
        Ls[c4 + 0][r] = f2bf(v.x);
        Ls[c4 + 1][r] = f2bf(v.y);
        Ls[c4 + 2][r] = f2bf(v.z);
        Ls[c4 + 3][r] = f2bf(v.w);
    }
    __syncthreads();
    const int n = t >> 2, kc = (t & 3) * 16;
    *(short8*)&Wt[(size_t)(n0 + n) * Kd + k0 + kc]     = *(const short8*)&Ls[n][kc];
    *(short8*)&Wt[(size_t)(n0 + n) * Kd + k0 + kc + 8] = *(const short8*)&Ls[n][kc + 8];
}

// ---------------------------------------------------------------------------
// bf16 MFMA GEMM: C = A[M][K] @ Bt[N][K]^T (+bias). m97 structure:
// 128x128 tile, BK=32, 4 waves (2x2, 64x64 each), global_load_lds(16B).
// ---------------------------------------------------------------------------
template <bool OUTF32>
__global__ __launch_bounds__(256) void gemm_bf16(
    const ushort* __restrict__ A, const ushort* __restrict__ Bt,
    const float* __restrict__ bias, void* __restrict__ Cout,
    int M, int N, int K)
{
    __shared__ ushort As[128 * 32];
    __shared__ ushort Bs[128 * 32];
    const int t = threadIdx.x;
    const int w = t >> 6, l = t & 63, lr = l & 15, lg = l >> 4;
    const int wr = w >> 1, wc = w & 1;
    const int n0 = blockIdx.x * 128, m0 = blockIdx.y * 128;

    // staging: chunk c -> row c>>2, k-offset (c&3)*8. Dest = wave-uniform base + lane*16B.
    const int c0 = w * 64 + l, c1 = c0 + 256;
    const ushort* a0 = &A[(size_t)(m0 + (c0 >> 2)) * K + (c0 & 3) * 8];
    const ushort* a1 = &A[(size_t)(m0 + (c1 >> 2)) * K + (c1 & 3) * 8];
    const ushort* b0 = &Bt[(size_t)(n0 + (c0 >> 2)) * K + (c0 & 3) * 8];
    const ushort* b1 = &Bt[(size_t)(n0 + (c1 >> 2)) * K + (c1 & 3) * 8];
    ushort* lA0 = &As[w * 512];
    ushort* lA1 = &As[(4 + w) * 512];
    ushort* lB0 = &Bs[w * 512];
    ushort* lB1 = &Bs[(4 + w) * 512];

    f32x4 acc[4][4];
    #pragma unroll
    for (int i = 0; i < 4; ++i)
        #pragma unroll
        for (int j = 0; j < 4; ++j) acc[i][j] = 0.f;

    for (int k0 = 0; k0 < K; k0 += 32) {
        __syncthreads();                 // prior frag reads done
        GL16(a0 + k0, lA0);
        GL16(a1 + k0, lA1);
        GL16(b0 + k0, lB0);
        GL16(b1 + k0, lB1);
        __syncthreads();                 // drains vmcnt(0): staging visible
        short8 af[4], bf[4];
        #pragma unroll
        for (int mi = 0; mi < 4; ++mi)
            af[mi] = *(const short8*)&As[(wr * 64 + mi * 16 + lr) * 32 + lg * 8];
        #pragma unroll
        for (int nj = 0; nj < 4; ++nj)
            bf[nj] = *(const short8*)&Bs[(wc * 64 + nj * 16 + lr) * 32 + lg * 8];
        #pragma unroll
        for (int mi = 0; mi < 4; ++mi)
            #pragma unroll
            for (int nj = 0; nj < 4; ++nj)
                acc[mi][nj] = __builtin_amdgcn_mfma_f32_16x16x32_bf16(
                    af[mi], bf[nj], acc[mi][nj], 0, 0, 0);
    }

    // C/D layout: col = lane&15, row = (lane>>4)*4 + r  [m89-verified]
    const int row0 = m0 + wr * 64, col0 = n0 + wc * 64;
    #pragma unroll
    for (int mi = 0; mi < 4; ++mi)
        #pragma unroll
        for (int nj = 0; nj < 4; ++nj) {
            const int col = col0 + nj * 16 + lr;
            #pragma unroll
            for (int r = 0; r < 4; ++r) {
                const int row = row0 + mi * 16 + lg * 4 + r;
                const float v = acc[mi][nj][r];
                if (OUTF32)
                    ((float*)Cout)[(size_t)row * N + col] = v + bias[col];
                else
                    ((ushort*)Cout)[(size_t)row * N + col] = f2bf(v);
            }
        }
}

// ---------------------------------------------------------------------------
// Classify each 64x64 mask tile: 0 = all masked, 1 = all pass, 2 = mixed.
// ---------------------------------------------------------------------------
__global__ __launch_bounds__(256) void mask_classify(
    const int* __restrict__ amask, const int* __restrict__ pmask,
    int* __restrict__ cls)
{
    const int bid = blockIdx.x;
    const int b = bid >> 10, xb = (bid >> 5) & 31, zb = bid & 31;
    const int t = threadIdx.x;
    int andv = 1, orv = 0;
    #pragma unroll
    for (int i = 0; i < 16; ++i) {
        int e = t + i * 256;
        int r = e >> 6, z = e & 63;
        int m = amask[((size_t)b * LX + xb * 64 + r) * LZ + zb * 64 + z];
        int p = pmask[(size_t)b * LZ + zb * 64 + z];
        int v = (m != 0) & (p != 0);
        andv &= v; orv |= v;
    }
    __shared__ int sa[256];
    __shared__ int so[256];
    sa[t] = andv; so[t] = orv;
    __syncthreads();
    for (int s = 128; s > 0; s >>= 1) {
        if (t < s) { sa[t] &= sa[t + s]; so[t] |= so[t + s]; }
        __syncthreads();
    }
    if (t == 0) cls[bid] = so[0] ? (sa[0] ? 1 : 2) : 0;
}

// ---------------------------------------------------------------------------
// MFMA flash attention. 256 thr = 4 waves; block = 128 q-rows; 64-wide KV tile.
// Wave w owns 32 q-rows. S = mfma(Q, K^T); online softmax in-register
// (row lives on 16 lanes, shfl_xor 1/2/4/8); P -> per-wave LDS -> A-frags;
// O += mfma(P, V) with V staged transposed.
// ---------------------------------------------------------------------------
__global__ __launch_bounds__(256) void attn_mfma(
    const ushort* __restrict__ Qg, const ushort* __restrict__ Kg,
    const ushort* __restrict__ Vg, const int* __restrict__ amask,
    const int* __restrict__ pmask, const int* __restrict__ cls,
    ushort* __restrict__ O)
{
    __shared__ ushort Ks[64 * 72];      // [z][d], pad 72 (2-way conflicts only)
    __shared__ ushort Vt[64 * 72];      // [m][z]
    __shared__ ushort Ps[4][32 * 72];   // per-wave P [q][z]

    const int qb = blockIdx.x, h = blockIdx.y, b = blockIdx.z;
    const int t = threadIdx.x, w = t >> 6, l = t & 63, lr = l & 15, lg = l >> 4;
    const int x0 = qb * 128;
    const int qw = x0 + w * 32;

    // Q A-frags from global: lane holds Q[row=lr][k=(lg)*8..+8] per (mi,ks)
    short8 qf[2][2];
    #pragma unroll
    for (int mi = 0; mi < 2; ++mi)
        #pragma unroll
        for (int ks = 0; ks < 2; ++ks)
            qf[mi][ks] = *(const short8*)&Qg[(size_t)(b * LX + qw + mi * 16 + lr) * HD
                                             + h * DA + ks * 32 + lg * 8];

    float mrun[2][4], lrun[2][4];
    f32x4 o[2][4];
    #pragma unroll
    for (int mi = 0; mi < 2; ++mi)
        #pragma unroll
        for (int r = 0; r < 4; ++r) { mrun[mi][r] = -1e30f; lrun[mi][r] = 0.f; }
    #pragma unroll
    for (int mi = 0; mi < 2; ++mi)
        #pragma unroll
        for (int mj = 0; mj < 4; ++mj) o[mi][mj] = 0.f;

    const int zrow = t >> 2, c16 = (t & 3) * 16;   // staging indices

    for (int zb = 0; zb < LZ / 64; ++zb) {
        const int cls0 = cls[b * 1024 + (qb * 2) * 32 + zb];
        const int cls1 = cls[b * 1024 + (qb * 2 + 1) * 32 + zb];
        if ((cls0 | cls1) == 0) continue;
        const int cl = (w < 2) ? cls0 : cls1;
        const int z0 = zb * 64;

        __syncthreads();                 // prior tile's frag reads done
        {
            const ushort* kp = &Kg[(size_t)(b * LZ + z0 + zrow) * HD + h * DA + c16];
            const ushort* vp = &Vg[(size_t)(b * LZ + z0 + zrow) * HD + h * DM + c16];
            short8 kv0 = *(const short8*)kp;
            short8 kv1 = *(const short8*)(kp + 8);
            short8 vv0 = *(const short8*)vp;
            short8 vv1 = *(const short8*)(vp + 8);
            *(short8*)&Ks[zrow * 72 + c16]     = kv0;
            *(short8*)&Ks[zrow * 72 + c16 + 8] = kv1;
            #pragma unroll
            for (int j = 0; j < 8; ++j) {
                Vt[(c16 + j) * 72 + zrow]     = (ushort)vv0[j];
                Vt[(c16 + 8 + j) * 72 + zrow] = (ushort)vv1[j];
            }
        }
        __syncthreads();

        if (cl) {
            // ---- S = Q @ K^T ----
            f32x4 s[2][4];
            #pragma unroll
            for (int nj = 0; nj < 4; ++nj) {
                short8 kf0 = *(const short8*)&Ks[(nj * 16 + lr) * 72 + lg * 8];
                short8 kf1 = *(const short8*)&Ks[(nj * 16 + lr) * 72 + 32 + lg * 8];
                #pragma unroll
                for (int mi = 0; mi < 2; ++mi) {
                    f32x4 z = 0.f;
                    z = __builtin_amdgcn_mfma_f32_16x16x32_bf16(qf[mi][0], kf0, z, 0, 0, 0);
                    z = __builtin_amdgcn_mfma_f32_16x16x32_bf16(qf[mi][1], kf1, z, 0, 0, 0);
                    s[mi][nj] = z;
                }
            }
            // ---- scale + mask ----
            if (cl == 2) {
                #pragma unroll
                for (int mi = 0; mi < 2; ++mi)
                    #pragma unroll
                    for (int r = 0; r < 4; ++r) {
                        const int q = qw + mi * 16 + lg * 4 + r;
                        const size_t mrow = (size_t)(b * LX + q) * LZ + z0;
                        #pragma unroll
                        for (int nj = 0; nj < 4; ++nj) {
                            const int z = nj * 16 + lr;
                            const int ok = (amask[mrow + z] != 0) & (pmask[b * LZ + z0 + z] != 0);
                            s[mi][nj][r] = ok ? s[mi][nj][r] * SCALE : MINF;
                        }
                    }
            } else {
                #pragma unroll
                for (int mi = 0; mi < 2; ++mi)
                    #pragma unroll
                    for (int nj = 0; nj < 4; ++nj) s[mi][nj] *= SCALE;
            }
            // ---- online softmax (row = 16 lanes sharing lg) ----
            #pragma unroll
            for (int mi = 0; mi < 2; ++mi)
                #pragma unroll
                for (int r = 0; r < 4; ++r) {
                    float mx = s[mi][0][r];
                    #pragma unroll
                    for (int nj = 1; nj < 4; ++nj) mx = fmaxf(mx, s[mi][nj][r]);
                    mx = fmaxf(mx, __shfl_xor(mx, 1));
                    mx = fmaxf(mx, __shfl_xor(mx, 2));
                    mx = fmaxf(mx, __shfl_xor(mx, 4));
                    mx = fmaxf(mx, __shfl_xor(mx, 8));
                    const float mn = fmaxf(mrun[mi][r], mx);
                    const float al = __expf(mrun[mi][r] - mn);
                    float sum = 0.f;
                    #pragma unroll
                    for (int nj = 0; nj < 4; ++nj) {
                        float p = __expf(s[mi][nj][r] - mn);
                        s[mi][nj][r] = p;
                        sum += p;
                    }
                    sum += __shfl_xor(sum, 1);
                    sum += __shfl_xor(sum, 2);
                    sum += __shfl_xor(sum, 4);
                    sum += __shfl_xor(sum, 8);
                    lrun[mi][r] = lrun[mi][r] * al + sum;
                    mrun[mi][r] = mn;
                    #pragma unroll
                    for (int mj = 0; mj < 4; ++mj) o[mi][mj][r] *= al;
                }
            // ---- P -> own LDS region (bf16), reread as A-frags ----
            #pragma unroll
            for (int mi = 0; mi < 2; ++mi)
                #pragma unroll
                for (int nj = 0; nj < 4; ++nj)
                    #pragma unroll
                    for (int r = 0; r < 4; ++r)
                        Ps[w][(mi * 16 + lg * 4 + r) * 72 + nj * 16 + lr] = f2bf(s[mi][nj][r]);
            short8 pa[2][2];
            #pragma unroll
            for (int mi = 0; mi < 2; ++mi) {
                pa[mi][0] = *(const short8*)&Ps[w][(mi * 16 + lr) * 72 + lg * 8];
                pa[mi][1] = *(const short8*)&Ps[w][(mi * 16 + lr) * 72 + 32 + lg * 8];
            }
            // ---- O += P @ V ----
            #pragma unroll
            for (int mj = 0; mj < 4; ++mj) {
                short8 vf0 = *(const short8*)&Vt[(mj * 16 + lr) * 72 + lg * 8];
                short8 vf1 = *(const short8*)&Vt[(mj * 16 + lr) * 72 + 32 + lg * 8];
                #pragma unroll
                for (int mi = 0; mi < 2; ++mi) {
                    o[mi][mj] = __builtin_amdgcn_mfma_f32_16x16x32_bf16(pa[mi][0], vf0, o[mi][mj], 0, 0, 0);
                    o[mi][mj] = __builtin_amdgcn_mfma_f32_16x16x32_bf16(pa[mi][1], vf1, o[mi][mj], 0, 0, 0);
                }
            }
        }
    }

    // ---- normalize + store bf16 ----
    #pragma unroll
    for (int mi = 0; mi < 2; ++mi) {
        float inv[4];
        #pragma unroll
        for (int r = 0; r < 4; ++r) inv[r] = 1.f / lrun[mi][r];
        #pragma unroll
        for (int mj = 0; mj < 4; ++mj)
            #pragma unroll
            for (int r = 0; r < 4; ++r)
                O[(size_t)(b * LX + qw + mi * 16 + lg * 4 + r) * HD + h * DM + mj * 16 + lr]
                    = f2bf(o[mi][mj][r] * inv[r]);
    }
}

// ---------------------------------------------------------------------------
extern "C" void kernel_launch(void* const* d_in, const int* in_sizes, int n_in,
                              void* d_out, int out_size, void* d_ws, size_t ws_size,
                              hipStream_t stream)
{
    const float* primary = (const float*)d_in[0];
    const float* context = (const float*)d_in[1];
    const int*   pmask   = (const int*)d_in[2];
    const int*   amask   = (const int*)d_in[3];
    const float* Wq      = (const float*)d_in[4];
    const float* Wk      = (const float*)d_in[5];
    const float* Wv      = (const float*)d_in[6];
    const float* Wo      = (const float*)d_in[7];
    const float* bo      = (const float*)d_in[8];
    float* out = (float*)d_out;

    char* w8 = (char*)d_ws;
    ushort* Pb  = (ushort*)(w8 + 0);          // 4096x1024 bf16 = 8 MB each
    ushort* Cb  = (ushort*)(w8 + 8388608);
    ushort* Qb  = (ushort*)(w8 + 16777216);
    ushort* Kb  = (ushort*)(w8 + 25165824);
    ushort* Vb  = (ushort*)(w8 + 33554432);
    ushort* AOb = (ushort*)(w8 + 41943040);
    ushort* Wqt = (ushort*)(w8 + 50331648);   // 1024x1024 bf16 = 2 MB each
    ushort* Wkt = (ushort*)(w8 + 52428800);
    ushort* Wvt = (ushort*)(w8 + 54525952);
    ushort* Wot = (ushort*)(w8 + 56623104);
    int*    clsp = (int*)(w8 + 58720256);

    const int M = NB * LX;                    // 4096

    f32_to_bf16_k<<<4096, 256, 0, stream>>>(primary, Pb, 1048576);
    f32_to_bf16_k<<<4096, 256, 0, stream>>>(context, Cb, 1048576);
    wtrans_k<<<dim3(16, 16), 256, 0, stream>>>(Wq, Wqt, 1024, 1024);
    wtrans_k<<<dim3(16, 16), 256, 0, stream>>>(Wk, Wkt, 1024, 1024);
    wtrans_k<<<dim3(16, 16), 256, 0, stream>>>(Wv, Wvt, 1024, 1024);
    wtrans_k<<<dim3(16, 16), 256, 0, stream>>>(Wo, Wot, 1024, 1024);

    dim3 gg(HD / 128, M / 128);               // (8, 32)
    gemm_bf16<false><<<gg, 256, 0, stream>>>(Pb, Wqt, nullptr, Qb, M, HD, 1024);
    gemm_bf16<false><<<gg, 256, 0, stream>>>(Cb, Wkt, nullptr, Kb, M, HD, 1024);
    gemm_bf16<false><<<gg, 256, 0, stream>>>(Cb, Wvt, nullptr, Vb, M, HD, 1024);

    mask_classify<<<NB * 32 * 32, 256, 0, stream>>>(amask, pmask, clsp);
    attn_mfma<<<dim3(LX / 128, HH, NB), 256, 0, stream>>>(Qb, Kb, Vb, amask, pmask, clsp, AOb);

    gemm_bf16<true><<<gg, 256, 0, stream>>>(AOb, Wot, bo, out, M, HD, 1024);
}

// Round 3
// 166.957 us; speedup vs baseline: 5.7320x; 1.5926x over previous
//
#include <hip/hip_runtime.h>

#define NB 2
#define LX 2048
#define LZ 2048
#define HH 16
#define DA 64
#define DM 64
#define HD 1024
#define MINF  -1000000.0f
#define QSC   0.1803368801f   // 0.125 * log2(e): softmax done in base-2 domain

typedef __attribute__((ext_vector_type(8))) short short8;
typedef __attribute__((ext_vector_type(4))) float f32x4;

static __device__ __forceinline__ ushort f2bf(float f) {
    union { float f; uint32_t u; } c; c.f = f;
    return (ushort)((c.u + 0x7FFFu + ((c.u >> 16) & 1u)) >> 16);
}

static __device__ __forceinline__ uint32_t cvtpk(float lo, float hi) {
    uint32_t r;
    asm("v_cvt_pk_bf16_f32 %0, %1, %2" : "=v"(r) : "v"(lo), "v"(hi));
    return r;
}

#define GL16(g, l) __builtin_amdgcn_global_load_lds( \
    (const __attribute__((address_space(1))) void*)(g), \
    (__attribute__((address_space(3))) void*)(l), 16, 0, 0)

// ---------------------------------------------------------------------------
// fp32 -> bf16 for both activations in one launch. 8192 blocks.
// ---------------------------------------------------------------------------
__global__ __launch_bounds__(256) void cvt_both(
    const float* __restrict__ pA, const float* __restrict__ pB,
    ushort* __restrict__ oA, ushort* __restrict__ oB)
{
    const int i = blockIdx.x * 256 + threadIdx.x;      // 0..2097151
    const float* in = (i < 1048576) ? pA : pB;
    ushort* out = (i < 1048576) ? oA : oB;
    const int j = i & 1048575;
    float4 v = ((const float4*)in)[j];
    ushort4 o;
    o.x = f2bf(v.x); o.y = f2bf(v.y); o.z = f2bf(v.z); o.w = f2bf(v.w);
    ((ushort4*)out)[j] = o;
}

// ---------------------------------------------------------------------------
// 4 weights W[1024][1024] f32 -> Wt[1024][1024] bf16 transposed, one launch.
// ---------------------------------------------------------------------------
__global__ __launch_bounds__(256) void wtrans4(
    const float* __restrict__ W0, const float* __restrict__ W1,
    const float* __restrict__ W2, const float* __restrict__ W3,
    ushort* __restrict__ T0, ushort* __restrict__ T1,
    ushort* __restrict__ T2, ushort* __restrict__ T3)
{
    const int zz = blockIdx.z;
    const float* W = (zz == 0) ? W0 : (zz == 1) ? W1 : (zz == 2) ? W2 : W3;
    ushort* Wt = (zz == 0) ? T0 : (zz == 1) ? T1 : (zz == 2) ? T2 : T3;

    __shared__ ushort Ls[64][72];
    const int n0 = blockIdx.x * 64, k0 = blockIdx.y * 64;
    const int t = threadIdx.x;
    const int rr = t >> 4, c4 = (t & 15) * 4;
    #pragma unroll
    for (int i = 0; i < 4; ++i) {
        const int r = rr + i * 16;
        float4 v = *(const float4*)&W[(size_t)(k0 + r) * 1024 + n0 + c4];
        Ls[c4 + 0][r] = f2bf(v.x);
        Ls[c4 + 1][r] = f2bf(v.y);
        Ls[c4 + 2][r] = f2bf(v.z);
        Ls[c4 + 3][r] = f2bf(v.w);
    }
    __syncthreads();
    const int n = t >> 2, kc = (t & 3) * 16;
    *(short8*)&Wt[(size_t)(n0 + n) * 1024 + k0 + kc]     = *(const short8*)&Ls[n][kc];
    *(short8*)&Wt[(size_t)(n0 + n) * 1024 + k0 + kc + 8] = *(const short8*)&Ls[n][kc + 8];
}

// ---------------------------------------------------------------------------
// bf16 MFMA GEMM body (m97 structure): C = A[M][1024] @ Bt[1024][1024]^T.
// 128x128 tile, BK=32, 4 waves, global_load_lds(16B). N=K=1024 hardcoded.
// ---------------------------------------------------------------------------
template <bool OUTF32>
static __device__ __forceinline__ void gemm_body(
    const ushort* __restrict__ A, const ushort* __restrict__ Bt,
    const float* __restrict__ bias, void* __restrict__ Cout, float osc)
{
    __shared__ ushort As[128 * 32];
    __shared__ ushort Bs[128 * 32];
    const int t = threadIdx.x;
    const int w = t >> 6, l = t & 63, lr = l & 15, lg = l >> 4;
    const int wr = w >> 1, wc = w & 1;
    const int n0 = blockIdx.x * 128, m0 = blockIdx.y * 128;

    const int c0 = t, c1 = t + 256;
    const ushort* a0 = &A[(size_t)(m0 + (c0 >> 2)) * 1024 + (c0 & 3) * 8];
    const ushort* a1 = &A[(size_t)(m0 + (c1 >> 2)) * 1024 + (c1 & 3) * 8];
    const ushort* b0 = &Bt[(size_t)(n0 + (c0 >> 2)) * 1024 + (c0 & 3) * 8];
    const ushort* b1 = &Bt[(size_t)(n0 + (c1 >> 2)) * 1024 + (c1 & 3) * 8];
    ushort* lA0 = &As[w * 512];
    ushort* lA1 = &As[(4 + w) * 512];
    ushort* lB0 = &Bs[w * 512];
    ushort* lB1 = &Bs[(4 + w) * 512];

    f32x4 acc[4][4];
    #pragma unroll
    for (int i = 0; i < 4; ++i)
        #pragma unroll
        for (int j = 0; j < 4; ++j) acc[i][j] = 0.f;

    for (int k0 = 0; k0 < 1024; k0 += 32) {
        __syncthreads();
        GL16(a0 + k0, lA0);
        GL16(a1 + k0, lA1);
        GL16(b0 + k0, lB0);
        GL16(b1 + k0, lB1);
        __syncthreads();
        short8 af[4], bf[4];
        #pragma unroll
        for (int mi = 0; mi < 4; ++mi)
            af[mi] = *(const short8*)&As[(wr * 64 + mi * 16 + lr) * 32 + lg * 8];
        #pragma unroll
        for (int nj = 0; nj < 4; ++nj)
            bf[nj] = *(const short8*)&Bs[(wc * 64 + nj * 16 + lr) * 32 + lg * 8];
        #pragma unroll
        for (int mi = 0; mi < 4; ++mi)
            #pragma unroll
            for (int nj = 0; nj < 4; ++nj)
                acc[mi][nj] = __builtin_amdgcn_mfma_f32_16x16x32_bf16(
                    af[mi], bf[nj], acc[mi][nj], 0, 0, 0);
    }

    const int row0 = m0 + wr * 64, col0 = n0 + wc * 64;
    #pragma unroll
    for (int mi = 0; mi < 4; ++mi)
        #pragma unroll
        for (int nj = 0; nj < 4; ++nj) {
            const int col = col0 + nj * 16 + lr;
            #pragma unroll
            for (int r = 0; r < 4; ++r) {
                const int row = row0 + mi * 16 + lg * 4 + r;
                const float v = acc[mi][nj][r];
                if (OUTF32)
                    ((float*)Cout)[(size_t)row * 1024 + col] = v + bias[col];
                else
                    ((ushort*)Cout)[(size_t)row * 1024 + col] = f2bf(v * osc);
            }
        }
}

__global__ __launch_bounds__(256) void gemm_qkv(
    const ushort* __restrict__ Pb, const ushort* __restrict__ Cb,
    const ushort* __restrict__ Wqt, const ushort* __restrict__ Wkt,
    const ushort* __restrict__ Wvt,
    ushort* __restrict__ Qb, ushort* __restrict__ Kb, ushort* __restrict__ Vb)
{
    const int z = blockIdx.z;
    const ushort* A  = (z == 0) ? Pb : Cb;
    const ushort* Bt = (z == 0) ? Wqt : (z == 1) ? Wkt : Wvt;
    ushort* C = (z == 0) ? Qb : (z == 1) ? Kb : Vb;
    const float osc = (z == 0) ? QSC : 1.0f;   // fold softmax scale*log2e into Q
    gemm_body<false>(A, Bt, nullptr, C, osc);
}

__global__ __launch_bounds__(256) void gemm_out(
    const ushort* __restrict__ A, const ushort* __restrict__ Bt,
    const float* __restrict__ bias, float* __restrict__ Cout)
{
    gemm_body<true>(A, Bt, bias, Cout, 1.0f);
}

// ---------------------------------------------------------------------------
// Classify each 64x64 mask tile: 0 = all masked, 1 = all pass, 2 = mixed.
// ---------------------------------------------------------------------------
__global__ __launch_bounds__(256) void mask_classify(
    const int* __restrict__ amask, const int* __restrict__ pmask,
    int* __restrict__ cls)
{
    const int bid = blockIdx.x;
    const int b = bid >> 10, xb = (bid >> 5) & 31, zb = bid & 31;
    const int t = threadIdx.x;
    int andv = 1, orv = 0;
    #pragma unroll
    for (int i = 0; i < 16; ++i) {
        const int e = t + i * 256;
        const int r = e >> 6, z = e & 63;
        const int m = amask[((size_t)b * LX + xb * 64 + r) * LZ + zb * 64 + z];
        const int p = pmask[(size_t)b * LZ + zb * 64 + z];
        const int v = (m != 0) & (p != 0);
        andv &= v; orv |= v;
    }
    __shared__ int sa[256];
    __shared__ int so[256];
    sa[t] = andv; so[t] = orv;
    __syncthreads();
    for (int s = 128; s > 0; s >>= 1) {
        if (t < s) { sa[t] &= sa[t + s]; so[t] |= so[t + s]; }
        __syncthreads();
    }
    if (t == 0) cls[bid] = so[0] ? (sa[0] ? 1 : 2) : 0;
}

// ---------------------------------------------------------------------------
// MFMA flash attention, swapped-QK^T + in-register P redistribution.
// 4 waves x 32 q-rows = 128 q-rows/block; 64-wide KV tiles.
// S^T = mfma(K, Q): lane holds S[q = mi*16+lr][z = nj*16+lg*4+r].
// Softmax: reduce over own 16 regs + shfl_xor(16,32). P -> PV A-frags via
// cvt_pk_bf16 + shfl_xor(16/32/48) (no LDS round trip). V staged with
// chunk-XOR swizzle f(m)=(m^(m>>3))&7 -> conflict-free b32 writes/b128 reads.
// Q projection is pre-scaled by 0.125*log2e, so softmax uses exp2f.
// ---------------------------------------------------------------------------
__global__ __launch_bounds__(256) void attn_mfma(
    const ushort* __restrict__ Qg, const ushort* __restrict__ Kg,
    const ushort* __restrict__ Vg, const int* __restrict__ amask,
    const int* __restrict__ pmask, const int* __restrict__ cls,
    ushort* __restrict__ O)
{
    __shared__ ushort Ks[64 * 72];   // [z][d], pad 72
    __shared__ ushort Vt[64 * 64];   // [m][z], chunk-XOR swizzled

    const int t = threadIdx.x, w = t >> 6, l = t & 63, lr = l & 15, lg = l >> 4;
    const int x = blockIdx.x, h = blockIdx.y, b = blockIdx.z;
    // load-balance remap: pairs (2c,2c+1) and (c,c+256) both sum to const work
    const int fx = (x & 1) ? 15 - (x >> 1) : (x >> 1);
    const int qb = b ? 15 - fx : fx;
    const int qw = qb * 128 + w * 32;

    // Q B-frags: lane holds Q[q = mi*16+lr][d = ks*32 + lg*8 .. +8]
    short8 qf[2][2];
    #pragma unroll
    for (int mi = 0; mi < 2; ++mi)
        #pragma unroll
        for (int ks = 0; ks < 2; ++ks)
            qf[mi][ks] = *(const short8*)&Qg[(size_t)(b * LX + qw + mi * 16 + lr) * HD
                                             + h * DA + ks * 32 + lg * 8];

    float mrun[2] = {-1e30f, -1e30f}, lrun[2] = {0.f, 0.f};
    f32x4 o[2][4];
    #pragma unroll
    for (int mi = 0; mi < 2; ++mi)
        #pragma unroll
        for (int mj = 0; mj < 4; ++mj) o[mi][mj] = 0.f;

    const int kz = t >> 2, kc = (t & 3) * 16;      // K staging
    const int vz = (t >> 3) * 2, vc = (t & 7) * 8; // V staging (2 rows x 8 cols)

    for (int zb = 0; zb < LZ / 64; ++zb) {
        const int cls0 = cls[b * 1024 + (qb * 2) * 32 + zb];
        const int cls1 = cls[b * 1024 + (qb * 2 + 1) * 32 + zb];
        if ((cls0 | cls1) == 0) continue;
        const int cl = (w < 2) ? cls0 : cls1;
        const int z0 = zb * 64;

        __syncthreads();                // prior tile's LDS reads done
        {
            const ushort* kp = &Kg[(size_t)(b * LZ + z0 + kz) * HD + h * DA + kc];
            *(short8*)&Ks[kz * 72 + kc]     = *(const short8*)kp;
            *(short8*)&Ks[kz * 72 + kc + 8] = *(const short8*)(kp + 8);
            const ushort* vp = &Vg[(size_t)(b * LZ + z0 + vz) * HD + h * DM + vc];
            short8 v0 = *(const short8*)vp;
            short8 v1 = *(const short8*)(vp + HD);
            const int zc = vz >> 3, zo = vz & 7;
            #pragma unroll
            for (int j = 0; j < 8; ++j) {
                const int m = vc + j;
                const int idx = m * 64 + (((zc ^ m ^ (m >> 3)) & 7) << 3) + zo;
                const uint32_t pr = (uint32_t)(ushort)v0[j] | ((uint32_t)(ushort)v1[j] << 16);
                *(uint32_t*)&Vt[idx] = pr;
            }
        }
        __syncthreads();
        if (!cl) continue;

        // ---- S^T = K @ Q ----
        f32x4 s[2][4];
        #pragma unroll
        for (int nj = 0; nj < 4; ++nj) {
            const short8 kf0 = *(const short8*)&Ks[(nj * 16 + lr) * 72 + lg * 8];
            const short8 kf1 = *(const short8*)&Ks[(nj * 16 + lr) * 72 + 32 + lg * 8];
            #pragma unroll
            for (int mi = 0; mi < 2; ++mi) {
                f32x4 z4 = 0.f;
                z4 = __builtin_amdgcn_mfma_f32_16x16x32_bf16(kf0, qf[mi][0], z4, 0, 0, 0);
                z4 = __builtin_amdgcn_mfma_f32_16x16x32_bf16(kf1, qf[mi][1], z4, 0, 0, 0);
                s[mi][nj] = z4;
            }
        }
        // ---- mask (mixed tiles only) ----
        if (cl == 2) {
            #pragma unroll
            for (int mi = 0; mi < 2; ++mi) {
                const size_t arow = (size_t)(b * LX + qw + mi * 16 + lr) * LZ + z0;
                #pragma unroll
                for (int nj = 0; nj < 4; ++nj)
                    #pragma unroll
                    for (int r = 0; r < 4; ++r) {
                        const int z = nj * 16 + lg * 4 + r;
                        const int ok = (amask[arow + z] != 0) & (pmask[b * LZ + z0 + z] != 0);
                        if (!ok) s[mi][nj][r] = MINF;
                    }
            }
        }
        // ---- online softmax (base-2; row = own 16 regs + lanes lg^1, lg^2) ----
        float al[2];
        #pragma unroll
        for (int mi = 0; mi < 2; ++mi) {
            float mx = s[mi][0][0];
            #pragma unroll
            for (int nj = 0; nj < 4; ++nj)
                #pragma unroll
                for (int r = 0; r < 4; ++r) mx = fmaxf(mx, s[mi][nj][r]);
            mx = fmaxf(mx, __shfl_xor(mx, 16));
            mx = fmaxf(mx, __shfl_xor(mx, 32));
            const float mn = fmaxf(mrun[mi], mx);
            al[mi] = exp2f(mrun[mi] - mn);
            float sum = 0.f;
            #pragma unroll
            for (int nj = 0; nj < 4; ++nj)
                #pragma unroll
                for (int r = 0; r < 4; ++r) {
                    const float p = exp2f(s[mi][nj][r] - mn);
                    s[mi][nj][r] = p;
                    sum += p;
                }
            sum += __shfl_xor(sum, 16);
            sum += __shfl_xor(sum, 32);
            lrun[mi] = lrun[mi] * al[mi] + sum;
            mrun[mi] = mn;
        }
        // ---- rescale O (al lives at q=lr; O rows are q=lg*4+r -> shfl) ----
        #pragma unroll
        for (int mi = 0; mi < 2; ++mi)
            #pragma unroll
            for (int r = 0; r < 4; ++r) {
                const float alq = __shfl(al[mi], (lg << 2) + r);
                #pragma unroll
                for (int mj = 0; mj < 4; ++mj) o[mi][mj][r] *= alq;
            }
        // ---- P -> PV A-frags in-register (cvt_pk + shfl_xor 16/32/48) ----
        short8 pa[2][2];
        #pragma unroll
        for (int mi = 0; mi < 2; ++mi) {
            uint32_t pk01[4], pk23[4];
            #pragma unroll
            for (int nj = 0; nj < 4; ++nj) {
                pk01[nj] = cvtpk(s[mi][nj][0], s[mi][nj][1]);
                pk23[nj] = cvtpk(s[mi][nj][2], s[mi][nj][3]);
            }
            const bool hi = (lg & 2) != 0;
            #pragma unroll
            for (int ks = 0; ks < 2; ++ks) {
                const uint32_t own01 = hi ? pk01[2 * ks + 1] : pk01[2 * ks];
                const uint32_t own23 = hi ? pk23[2 * ks + 1] : pk23[2 * ks];
                const uint32_t oth01 = hi ? pk01[2 * ks]     : pk01[2 * ks + 1];
                const uint32_t oth23 = hi ? pk23[2 * ks]     : pk23[2 * ks + 1];
                const uint32_t x16a = (uint32_t)__shfl_xor((int)own01, 16);
                const uint32_t x16b = (uint32_t)__shfl_xor((int)own23, 16);
                const uint32_t x32a = (uint32_t)__shfl_xor((int)oth01, 32);
                const uint32_t x32b = (uint32_t)__shfl_xor((int)oth23, 32);
                const uint32_t x48a = (uint32_t)__shfl_xor((int)oth01, 48);
                const uint32_t x48b = (uint32_t)__shfl_xor((int)oth23, 48);
                union { uint32_t d[4]; short8 v; } u;
                u.d[0] = (lg == 0) ? own01 : (lg == 1) ? x48a : (lg == 2) ? x32a : x16a;
                u.d[1] = (lg == 0) ? own23 : (lg == 1) ? x48b : (lg == 2) ? x32b : x16b;
                u.d[2] = (lg == 0) ? x16a : (lg == 1) ? x32a : (lg == 2) ? x48a : own01;
                u.d[3] = (lg == 0) ? x16b : (lg == 1) ? x32b : (lg == 2) ? x48b : own23;
                pa[mi][ks] = u.v;
            }
        }
        // ---- O += P @ V ----
        #pragma unroll
        for (int mj = 0; mj < 4; ++mj) {
            const int m_ = mj * 16 + lr;
            const int fs = (m_ ^ (m_ >> 3)) & 7;
            const short8 vf0 = *(const short8*)&Vt[m_ * 64 + ((lg ^ fs) << 3)];
            const short8 vf1 = *(const short8*)&Vt[m_ * 64 + (((4 + lg) ^ fs) << 3)];
            #pragma unroll
            for (int mi = 0; mi < 2; ++mi) {
                o[mi][mj] = __builtin_amdgcn_mfma_f32_16x16x32_bf16(pa[mi][0], vf0, o[mi][mj], 0, 0, 0);
                o[mi][mj] = __builtin_amdgcn_mfma_f32_16x16x32_bf16(pa[mi][1], vf1, o[mi][mj], 0, 0, 0);
            }
        }
    }

    // ---- normalize + store (l lives at q=lr; O rows are q=lg*4+r -> shfl) ----
    #pragma unroll
    for (int mi = 0; mi < 2; ++mi) {
        const float linv = 1.f / lrun[mi];
        #pragma unroll
        for (int r = 0; r < 4; ++r) {
            const float iq = __shfl(linv, (lg << 2) + r);
            #pragma unroll
            for (int mj = 0; mj < 4; ++mj)
                O[(size_t)(b * LX + qw + mi * 16 + (lg << 2) + r) * HD + h * DM + mj * 16 + lr]
                    = f2bf(o[mi][mj][r] * iq);
        }
    }
}

// ---------------------------------------------------------------------------
extern "C" void kernel_launch(void* const* d_in, const int* in_sizes, int n_in,
                              void* d_out, int out_size, void* d_ws, size_t ws_size,
                              hipStream_t stream)
{
    const float* primary = (const float*)d_in[0];
    const float* context = (const float*)d_in[1];
    const int*   pmask   = (const int*)d_in[2];
    const int*   amask   = (const int*)d_in[3];
    const float* Wq      = (const float*)d_in[4];
    const float* Wk      = (const float*)d_in[5];
    const float* Wv      = (const float*)d_in[6];
    const float* Wo      = (const float*)d_in[7];
    const float* bo      = (const float*)d_in[8];
    float* out = (float*)d_out;

    char* w8 = (char*)d_ws;
    ushort* Pb  = (ushort*)(w8 + 0);
    ushort* Cb  = (ushort*)(w8 + 8388608);
    ushort* Qb  = (ushort*)(w8 + 16777216);
    ushort* Kb  = (ushort*)(w8 + 25165824);
    ushort* Vb  = (ushort*)(w8 + 33554432);
    ushort* AOb = (ushort*)(w8 + 41943040);
    ushort* Wqt = (ushort*)(w8 + 50331648);
    ushort* Wkt = (ushort*)(w8 + 52428800);
    ushort* Wvt = (ushort*)(w8 + 54525952);
    ushort* Wot = (ushort*)(w8 + 56623104);
    int*    clsp = (int*)(w8 + 58720256);

    cvt_both<<<8192, 256, 0, stream>>>(primary, context, Pb, Cb);
    wtrans4<<<dim3(16, 16, 4), 256, 0, stream>>>(Wq, Wk, Wv, Wo, Wqt, Wkt, Wvt, Wot);
    mask_classify<<<NB * 32 * 32, 256, 0, stream>>>(amask, pmask, clsp);
    gemm_qkv<<<dim3(8, 32, 3), 256, 0, stream>>>(Pb, Cb, Wqt, Wkt, Wvt, Qb, Kb, Vb);
    attn_mfma<<<dim3(16, 16, 2), 256, 0, stream>>>(Qb, Kb, Vb, amask, pmask, clsp, AOb);
    gemm_out<<<dim3(8, 32), 256, 0, stream>>>(AOb, Wot, bo, out);
}

// Round 4
// 155.107 us; speedup vs baseline: 6.1699x; 1.0764x over previous
//
#include <hip/hip_runtime.h>

#define NB 2
#define LX 2048
#define LZ 2048
#define HH 16
#define DA 64
#define DM 64
#define HD 1024
#define MINF  -1000000.0f
#define QSC   0.1803368801f   // 0.125 * log2(e): softmax done in base-2 domain
#define DTHR  8.0f            // defer-max threshold (base-2): P <= 2^8

typedef __attribute__((ext_vector_type(8))) short short8;
typedef __attribute__((ext_vector_type(4))) float f32x4;

static __device__ __forceinline__ ushort f2bf(float f) {
    union { float f; uint32_t u; } c; c.f = f;
    return (ushort)((c.u + 0x7FFFu + ((c.u >> 16) & 1u)) >> 16);
}

static __device__ __forceinline__ uint32_t cvtpk(float lo, float hi) {
    uint32_t r;
    asm("v_cvt_pk_bf16_f32 %0, %1, %2" : "=v"(r) : "v"(lo), "v"(hi));
    return r;
}

#define GL16(g, l) __builtin_amdgcn_global_load_lds( \
    (const __attribute__((address_space(1))) void*)(g), \
    (__attribute__((address_space(3))) void*)(l), 16, 0, 0)

// ---------------------------------------------------------------------------
// fp32 -> bf16 for both activations in one launch. 8192 blocks.
// ---------------------------------------------------------------------------
__global__ __launch_bounds__(256) void cvt_both(
    const float* __restrict__ pA, const float* __restrict__ pB,
    ushort* __restrict__ oA, ushort* __restrict__ oB)
{
    const int i = blockIdx.x * 256 + threadIdx.x;      // 0..2097151
    const float* in = (i < 1048576) ? pA : pB;
    ushort* out = (i < 1048576) ? oA : oB;
    const int j = i & 1048575;
    float4 v = ((const float4*)in)[j];
    ushort4 o;
    o.x = f2bf(v.x); o.y = f2bf(v.y); o.z = f2bf(v.z); o.w = f2bf(v.w);
    ((ushort4*)out)[j] = o;
}

// ---------------------------------------------------------------------------
// 4 weights W[1024][1024] f32 -> Wt[1024][1024] bf16 transposed, one launch.
// ---------------------------------------------------------------------------
__global__ __launch_bounds__(256) void wtrans4(
    const float* __restrict__ W0, const float* __restrict__ W1,
    const float* __restrict__ W2, const float* __restrict__ W3,
    ushort* __restrict__ T0, ushort* __restrict__ T1,
    ushort* __restrict__ T2, ushort* __restrict__ T3)
{
    const int zz = blockIdx.z;
    const float* W = (zz == 0) ? W0 : (zz == 1) ? W1 : (zz == 2) ? W2 : W3;
    ushort* Wt = (zz == 0) ? T0 : (zz == 1) ? T1 : (zz == 2) ? T2 : T3;

    __shared__ ushort Ls[64][72];
    const int n0 = blockIdx.x * 64, k0 = blockIdx.y * 64;
    const int t = threadIdx.x;
    const int rr = t >> 4, c4 = (t & 15) * 4;
    #pragma unroll
    for (int i = 0; i < 4; ++i) {
        const int r = rr + i * 16;
        float4 v = *(const float4*)&W[(size_t)(k0 + r) * 1024 + n0 + c4];
        Ls[c4 + 0][r] = f2bf(v.x);
        Ls[c4 + 1][r] = f2bf(v.y);
        Ls[c4 + 2][r] = f2bf(v.z);
        Ls[c4 + 3][r] = f2bf(v.w);
    }
    __syncthreads();
    const int n = t >> 2, kc = (t & 3) * 16;
    *(short8*)&Wt[(size_t)(n0 + n) * 1024 + k0 + kc]     = *(const short8*)&Ls[n][kc];
    *(short8*)&Wt[(size_t)(n0 + n) * 1024 + k0 + kc + 8] = *(const short8*)&Ls[n][kc + 8];
}

// ---------------------------------------------------------------------------
// bf16 MFMA GEMM body (m97 structure): C = A[M][1024] @ Bt[1024][1024]^T.
// 128x128 tile, BK=32, 4 waves, global_load_lds(16B). N=K=1024 hardcoded.
// ---------------------------------------------------------------------------
template <bool OUTF32>
static __device__ __forceinline__ void gemm_body(
    const ushort* __restrict__ A, const ushort* __restrict__ Bt,
    const float* __restrict__ bias, void* __restrict__ Cout, float osc)
{
    __shared__ ushort As[128 * 32];
    __shared__ ushort Bs[128 * 32];
    const int t = threadIdx.x;
    const int w = t >> 6, l = t & 63, lr = l & 15, lg = l >> 4;
    const int wr = w >> 1, wc = w & 1;
    const int n0 = blockIdx.x * 128, m0 = blockIdx.y * 128;

    const int c0 = t, c1 = t + 256;
    const ushort* a0 = &A[(size_t)(m0 + (c0 >> 2)) * 1024 + (c0 & 3) * 8];
    const ushort* a1 = &A[(size_t)(m0 + (c1 >> 2)) * 1024 + (c1 & 3) * 8];
    const ushort* b0 = &Bt[(size_t)(n0 + (c0 >> 2)) * 1024 + (c0 & 3) * 8];
    const ushort* b1 = &Bt[(size_t)(n0 + (c1 >> 2)) * 1024 + (c1 & 3) * 8];
    ushort* lA0 = &As[w * 512];
    ushort* lA1 = &As[(4 + w) * 512];
    ushort* lB0 = &Bs[w * 512];
    ushort* lB1 = &Bs[(4 + w) * 512];

    f32x4 acc[4][4];
    #pragma unroll
    for (int i = 0; i < 4; ++i)
        #pragma unroll
        for (int j = 0; j < 4; ++j) acc[i][j] = 0.f;

    for (int k0 = 0; k0 < 1024; k0 += 32) {
        __syncthreads();
        GL16(a0 + k0, lA0);
        GL16(a1 + k0, lA1);
        GL16(b0 + k0, lB0);
        GL16(b1 + k0, lB1);
        __syncthreads();
        short8 af[4], bf[4];
        #pragma unroll
        for (int mi = 0; mi < 4; ++mi)
            af[mi] = *(const short8*)&As[(wr * 64 + mi * 16 + lr) * 32 + lg * 8];
        #pragma unroll
        for (int nj = 0; nj < 4; ++nj)
            bf[nj] = *(const short8*)&Bs[(wc * 64 + nj * 16 + lr) * 32 + lg * 8];
        #pragma unroll
        for (int mi = 0; mi < 4; ++mi)
            #pragma unroll
            for (int nj = 0; nj < 4; ++nj)
                acc[mi][nj] = __builtin_amdgcn_mfma_f32_16x16x32_bf16(
                    af[mi], bf[nj], acc[mi][nj], 0, 0, 0);
    }

    const int row0 = m0 + wr * 64, col0 = n0 + wc * 64;
    #pragma unroll
    for (int mi = 0; mi < 4; ++mi)
        #pragma unroll
        for (int nj = 0; nj < 4; ++nj) {
            const int col = col0 + nj * 16 + lr;
            #pragma unroll
            for (int r = 0; r < 4; ++r) {
                const int row = row0 + mi * 16 + lg * 4 + r;
                const float v = acc[mi][nj][r];
                if (OUTF32)
                    ((float*)Cout)[(size_t)row * 1024 + col] = v + bias[col];
                else
                    ((ushort*)Cout)[(size_t)row * 1024 + col] = f2bf(v * osc);
            }
        }
}

__global__ __launch_bounds__(256) void gemm_qkv(
    const ushort* __restrict__ Pb, const ushort* __restrict__ Cb,
    const ushort* __restrict__ Wqt, const ushort* __restrict__ Wkt,
    const ushort* __restrict__ Wvt,
    ushort* __restrict__ Qb, ushort* __restrict__ Kb, ushort* __restrict__ Vb)
{
    const int z = blockIdx.z;
    const ushort* A  = (z == 0) ? Pb : Cb;
    const ushort* Bt = (z == 0) ? Wqt : (z == 1) ? Wkt : Wvt;
    ushort* C = (z == 0) ? Qb : (z == 1) ? Kb : Vb;
    const float osc = (z == 0) ? QSC : 1.0f;   // fold softmax scale*log2e into Q
    gemm_body<false>(A, Bt, nullptr, C, osc);
}

__global__ __launch_bounds__(256) void gemm_out(
    const ushort* __restrict__ A, const ushort* __restrict__ Bt,
    const float* __restrict__ bias, float* __restrict__ Cout)
{
    gemm_body<true>(A, Bt, bias, Cout, 1.0f);
}

// ---------------------------------------------------------------------------
// Classify each 64x64 mask tile: 0 = all masked, 1 = all pass, 2 = mixed.
// ---------------------------------------------------------------------------
__global__ __launch_bounds__(256) void mask_classify(
    const int* __restrict__ amask, const int* __restrict__ pmask,
    int* __restrict__ cls)
{
    const int bid = blockIdx.x;
    const int b = bid >> 10, xb = (bid >> 5) & 31, zb = bid & 31;
    const int t = threadIdx.x;
    int andv = 1, orv = 0;
    #pragma unroll
    for (int i = 0; i < 16; ++i) {
        const int e = t + i * 256;
        const int r = e >> 6, z = e & 63;
        const int m = amask[((size_t)b * LX + xb * 64 + r) * LZ + zb * 64 + z];
        const int p = pmask[(size_t)b * LZ + zb * 64 + z];
        const int v = (m != 0) & (p != 0);
        andv &= v; orv |= v;
    }
    __shared__ int sa[256];
    __shared__ int so[256];
    sa[t] = andv; so[t] = orv;
    __syncthreads();
    for (int s = 128; s > 0; s >>= 1) {
        if (t < s) { sa[t] &= sa[t + s]; so[t] |= so[t + s]; }
        __syncthreads();
    }
    if (t == 0) cls[bid] = so[0] ? (sa[0] ? 1 : 2) : 0;
}

// ---------------------------------------------------------------------------
// MFMA flash attention. Swapped QK^T; P stays lane-local for PV via the
// z-permutation trick: MFMA contracts A/B slot-wise per lane-group, so we
// choose slot z-order zeta(lg,ks,j) = ks*32 + (j>=4)*16 + lg*4 + (j&3) --
// each lane's PV A-frag is exactly its own softmax registers (no shfl,
// no cndmask). V-frags read the matching permuted z-runs as 4x ds_read_b64
// from the (unchanged) chunk-XOR-swizzled Vt. Defer-max (THR=8, base-2)
// skips most O-rescales; setprio(1) wraps both MFMA clusters.
// ---------------------------------------------------------------------------
__global__ __launch_bounds__(256) void attn_mfma(
    const ushort* __restrict__ Qg, const ushort* __restrict__ Kg,
    const ushort* __restrict__ Vg, const int* __restrict__ amask,
    const int* __restrict__ pmask, const int* __restrict__ cls,
    ushort* __restrict__ O)
{
    __shared__ ushort Ks[64 * 72];   // [z][d], pad 72
    __shared__ ushort Vt[64 * 64];   // [m][z], chunk-XOR swizzled

    const int t = threadIdx.x, w = t >> 6, l = t & 63, lr = l & 15, lg = l >> 4;
    const int x = blockIdx.x, h = blockIdx.y, b = blockIdx.z;
    // load-balance remap: pairs (2c,2c+1) and (c,c+256) both sum to const work
    const int fx = (x & 1) ? 15 - (x >> 1) : (x >> 1);
    const int qb = b ? 15 - fx : fx;
    const int qw = qb * 128 + w * 32;

    // Q B-frags: lane holds Q[q = mi*16+lr][d = ks*32 + lg*8 .. +8]
    short8 qf[2][2];
    #pragma unroll
    for (int mi = 0; mi < 2; ++mi)
        #pragma unroll
        for (int ks = 0; ks < 2; ++ks)
            qf[mi][ks] = *(const short8*)&Qg[(size_t)(b * LX + qw + mi * 16 + lr) * HD
                                             + h * DA + ks * 32 + lg * 8];

    float mrun[2] = {-1e30f, -1e30f}, lrun[2] = {0.f, 0.f};
    f32x4 o[2][4];
    #pragma unroll
    for (int mi = 0; mi < 2; ++mi)
        #pragma unroll
        for (int mj = 0; mj < 4; ++mj) o[mi][mj] = 0.f;

    const int kz = t >> 2, kc = (t & 3) * 16;      // K staging
    const int vz = (t >> 3) * 2, vc = (t & 7) * 8; // V staging (2 rows x 8 cols)

    for (int zb = 0; zb < LZ / 64; ++zb) {
        const int cls0 = cls[b * 1024 + (qb * 2) * 32 + zb];
        const int cls1 = cls[b * 1024 + (qb * 2 + 1) * 32 + zb];
        if ((cls0 | cls1) == 0) continue;
        const int cl = (w < 2) ? cls0 : cls1;
        const int z0 = zb * 64;

        __syncthreads();                // prior tile's LDS reads done
        {
            const ushort* kp = &Kg[(size_t)(b * LZ + z0 + kz) * HD + h * DA + kc];
            *(short8*)&Ks[kz * 72 + kc]     = *(const short8*)kp;
            *(short8*)&Ks[kz * 72 + kc + 8] = *(const short8*)(kp + 8);
            const ushort* vp = &Vg[(size_t)(b * LZ + z0 + vz) * HD + h * DM + vc];
            short8 v0 = *(const short8*)vp;
            short8 v1 = *(const short8*)(vp + HD);
            const int zc = vz >> 3, zo = vz & 7;
            #pragma unroll
            for (int j = 0; j < 8; ++j) {
                const int m = vc + j;
                const int idx = m * 64 + (((zc ^ m ^ (m >> 3)) & 7) << 3) + zo;
                const uint32_t pr = (uint32_t)(ushort)v0[j] | ((uint32_t)(ushort)v1[j] << 16);
                *(uint32_t*)&Vt[idx] = pr;
            }
        }
        __syncthreads();
        if (!cl) continue;

        // ---- S^T = K @ Q ----
        f32x4 s[2][4];
        __builtin_amdgcn_s_setprio(1);
        #pragma unroll
        for (int nj = 0; nj < 4; ++nj) {
            const short8 kf0 = *(const short8*)&Ks[(nj * 16 + lr) * 72 + lg * 8];
            const short8 kf1 = *(const short8*)&Ks[(nj * 16 + lr) * 72 + 32 + lg * 8];
            #pragma unroll
            for (int mi = 0; mi < 2; ++mi) {
                f32x4 z4 = 0.f;
                z4 = __builtin_amdgcn_mfma_f32_16x16x32_bf16(kf0, qf[mi][0], z4, 0, 0, 0);
                z4 = __builtin_amdgcn_mfma_f32_16x16x32_bf16(kf1, qf[mi][1], z4, 0, 0, 0);
                s[mi][nj] = z4;
            }
        }
        __builtin_amdgcn_s_setprio(0);
        // ---- mask (mixed tiles only) ----
        if (cl == 2) {
            #pragma unroll
            for (int mi = 0; mi < 2; ++mi) {
                const size_t arow = (size_t)(b * LX + qw + mi * 16 + lr) * LZ + z0;
                #pragma unroll
                for (int nj = 0; nj < 4; ++nj)
                    #pragma unroll
                    for (int r = 0; r < 4; ++r) {
                        const int z = nj * 16 + lg * 4 + r;
                        const int ok = (amask[arow + z] != 0) & (pmask[b * LZ + z0 + z] != 0);
                        if (!ok) s[mi][nj][r] = MINF;
                    }
            }
        }
        // ---- online softmax, base-2, defer-max (row stats live at q=lr) ----
        #pragma unroll
        for (int mi = 0; mi < 2; ++mi) {
            float pm = s[mi][0][0];
            #pragma unroll
            for (int nj = 0; nj < 4; ++nj)
                #pragma unroll
                for (int r = 0; r < 4; ++r) pm = fmaxf(pm, s[mi][nj][r]);
            pm = fmaxf(pm, __shfl_xor(pm, 16));
            pm = fmaxf(pm, __shfl_xor(pm, 32));
            if (__any(pm > mrun[mi] + DTHR)) {
                const float mn = fmaxf(mrun[mi], pm);
                const float al = exp2f(mrun[mi] - mn);
                mrun[mi] = mn;
                lrun[mi] *= al;
                #pragma unroll
                for (int r = 0; r < 4; ++r) {
                    const float alq = __shfl(al, (lg << 2) + r);
                    #pragma unroll
                    for (int mj = 0; mj < 4; ++mj) o[mi][mj][r] *= alq;
                }
            }
            float sum = 0.f;
            #pragma unroll
            for (int nj = 0; nj < 4; ++nj)
                #pragma unroll
                for (int r = 0; r < 4; ++r) {
                    const float p = exp2f(s[mi][nj][r] - mrun[mi]);
                    s[mi][nj][r] = p;
                    sum += p;
                }
            sum += __shfl_xor(sum, 16);
            sum += __shfl_xor(sum, 32);
            lrun[mi] += sum;
        }
        // ---- P -> PV A-frags: pack own registers (sigma z-order) ----
        short8 pa[2][2];
        #pragma unroll
        for (int mi = 0; mi < 2; ++mi) {
            uint32_t pk01[4], pk23[4];
            #pragma unroll
            for (int nj = 0; nj < 4; ++nj) {
                pk01[nj] = cvtpk(s[mi][nj][0], s[mi][nj][1]);
                pk23[nj] = cvtpk(s[mi][nj][2], s[mi][nj][3]);
            }
            #pragma unroll
            for (int ks = 0; ks < 2; ++ks) {
                union { uint32_t d[4]; short8 v; } u;
                u.d[0] = pk01[2 * ks];
                u.d[1] = pk23[2 * ks];
                u.d[2] = pk01[2 * ks + 1];
                u.d[3] = pk23[2 * ks + 1];
                pa[mi][ks] = u.v;
            }
        }
        // ---- O += P @ V (V-frags in matching sigma z-order, 4x b64 each) ----
        __builtin_amdgcn_s_setprio(1);
        #pragma unroll
        for (int mj = 0; mj < 4; ++mj) {
            const int m_ = mj * 16 + lr;
            const int xr = (m_ ^ (m_ >> 3)) & 7;
            const int czb = lg >> 1;             // (lg*4)>>3
            const int zo = (lg & 1) * 4;
            #pragma unroll
            for (int ks = 0; ks < 2; ++ks) {
                const int clo = (ks * 4 + czb) ^ xr;
                const int chi = (ks * 4 + 2 + czb) ^ xr;
                const uint2 lo = *(const uint2*)&Vt[m_ * 64 + ((clo & 7) << 3) + zo];
                const uint2 hi = *(const uint2*)&Vt[m_ * 64 + ((chi & 7) << 3) + zo];
                union { uint32_t d[4]; short8 v; } u;
                u.d[0] = lo.x; u.d[1] = lo.y; u.d[2] = hi.x; u.d[3] = hi.y;
                #pragma unroll
                for (int mi = 0; mi < 2; ++mi)
                    o[mi][mj] = __builtin_amdgcn_mfma_f32_16x16x32_bf16(
                        pa[mi][ks], u.v, o[mi][mj], 0, 0, 0);
            }
        }
        __builtin_amdgcn_s_setprio(0);
    }

    // ---- normalize + store (l lives at q=lr; O rows are q=lg*4+r -> shfl) ----
    #pragma unroll
    for (int mi = 0; mi < 2; ++mi) {
        const float linv = 1.f / lrun[mi];
        #pragma unroll
        for (int r = 0; r < 4; ++r) {
            const float iq = __shfl(linv, (lg << 2) + r);
            #pragma unroll
            for (int mj = 0; mj < 4; ++mj)
                O[(size_t)(b * LX + qw + mi * 16 + (lg << 2) + r) * HD + h * DM + mj * 16 + lr]
                    = f2bf(o[mi][mj][r] * iq);
        }
    }
}

// ---------------------------------------------------------------------------
extern "C" void kernel_launch(void* const* d_in, const int* in_sizes, int n_in,
                              void* d_out, int out_size, void* d_ws, size_t ws_size,
                              hipStream_t stream)
{
    const float* primary = (const float*)d_in[0];
    const float* context = (const float*)d_in[1];
    const int*   pmask   = (const int*)d_in[2];
    const int*   amask   = (const int*)d_in[3];
    const float* Wq      = (const float*)d_in[4];
    const float* Wk      = (const float*)d_in[5];
    const float* Wv      = (const float*)d_in[6];
    const float* Wo      = (const float*)d_in[7];
    const float* bo      = (const float*)d_in[8];
    float* out = (float*)d_out;

    char* w8 = (char*)d_ws;
    ushort* Pb  = (ushort*)(w8 + 0);
    ushort* Cb  = (ushort*)(w8 + 8388608);
    ushort* Qb  = (ushort*)(w8 + 16777216);
    ushort* Kb  = (ushort*)(w8 + 25165824);
    ushort* Vb  = (ushort*)(w8 + 33554432);
    ushort* AOb = (ushort*)(w8 + 41943040);
    ushort* Wqt = (ushort*)(w8 + 50331648);
    ushort* Wkt = (ushort*)(w8 + 52428800);
    ushort* Wvt = (ushort*)(w8 + 54525952);
    ushort* Wot = (ushort*)(w8 + 56623104);
    int*    clsp = (int*)(w8 + 58720256);

    cvt_both<<<8192, 256, 0, stream>>>(primary, context, Pb, Cb);
    wtrans4<<<dim3(16, 16, 4), 256, 0, stream>>>(Wq, Wk, Wv, Wo, Wqt, Wkt, Wvt, Wot);
    mask_classify<<<NB * 32 * 32, 256, 0, stream>>>(amask, pmask, clsp);
    gemm_qkv<<<dim3(8, 32, 3), 256, 0, stream>>>(Pb, Cb, Wqt, Wkt, Wvt, Qb, Kb, Vb);
    attn_mfma<<<dim3(16, 16, 2), 256, 0, stream>>>(Qb, Kb, Vb, amask, pmask, clsp, AOb);
    gemm_out<<<dim3(8, 32), 256, 0, stream>>>(AOb, Wot, bo, out);
}

// Round 5
// 139.017 us; speedup vs baseline: 6.8840x; 1.1157x over previous
//
#include <hip/hip_runtime.h>

#define NB 2
#define LX 2048
#define LZ 2048
#define HH 16
#define DA 64
#define DM 64
#define HD 1024
#define MINF  -1000000.0f
#define QSC   0.1803368801f   // 0.125 * log2(e): softmax done in base-2 domain
#define DTHR  8.0f            // defer-max threshold (base-2): P <= 2^8

typedef __attribute__((ext_vector_type(8))) short short8;
typedef __attribute__((ext_vector_type(4))) float f32x4;

static __device__ __forceinline__ ushort f2bf(float f) {
    union { float f; uint32_t u; } c; c.f = f;
    return (ushort)((c.u + 0x7FFFu + ((c.u >> 16) & 1u)) >> 16);
}

static __device__ __forceinline__ uint32_t cvtpk(float lo, float hi) {
    uint32_t r;
    asm("v_cvt_pk_bf16_f32 %0, %1, %2" : "=v"(r) : "v"(lo), "v"(hi));
    return r;
}

#define GL16(g, l) __builtin_amdgcn_global_load_lds( \
    (const __attribute__((address_space(1))) void*)(g), \
    (__attribute__((address_space(3))) void*)(l), 16, 0, 0)

// ---------------------------------------------------------------------------
// fp32 -> bf16 for both activations in one launch. 8192 blocks.
// ---------------------------------------------------------------------------
__global__ __launch_bounds__(256) void cvt_both(
    const float* __restrict__ pA, const float* __restrict__ pB,
    ushort* __restrict__ oA, ushort* __restrict__ oB)
{
    const int i = blockIdx.x * 256 + threadIdx.x;      // 0..2097151
    const float* in = (i < 1048576) ? pA : pB;
    ushort* out = (i < 1048576) ? oA : oB;
    const int j = i & 1048575;
    float4 v = ((const float4*)in)[j];
    ushort4 o;
    o.x = f2bf(v.x); o.y = f2bf(v.y); o.z = f2bf(v.z); o.w = f2bf(v.w);
    ((ushort4*)out)[j] = o;
}

// ---------------------------------------------------------------------------
// 4 weights W[1024][1024] f32 -> Wt[1024][1024] bf16 transposed, one launch.
// ---------------------------------------------------------------------------
__global__ __launch_bounds__(256) void wtrans4(
    const float* __restrict__ W0, const float* __restrict__ W1,
    const float* __restrict__ W2, const float* __restrict__ W3,
    ushort* __restrict__ T0, ushort* __restrict__ T1,
    ushort* __restrict__ T2, ushort* __restrict__ T3)
{
    const int zz = blockIdx.z;
    const float* W = (zz == 0) ? W0 : (zz == 1) ? W1 : (zz == 2) ? W2 : W3;
    ushort* Wt = (zz == 0) ? T0 : (zz == 1) ? T1 : (zz == 2) ? T2 : T3;

    __shared__ ushort Ls[64][72];
    const int n0 = blockIdx.x * 64, k0 = blockIdx.y * 64;
    const int t = threadIdx.x;
    const int rr = t >> 4, c4 = (t & 15) * 4;
    #pragma unroll
    for (int i = 0; i < 4; ++i) {
        const int r = rr + i * 16;
        float4 v = *(const float4*)&W[(size_t)(k0 + r) * 1024 + n0 + c4];
        Ls[c4 + 0][r] = f2bf(v.x);
        Ls[c4 + 1][r] = f2bf(v.y);
        Ls[c4 + 2][r] = f2bf(v.z);
        Ls[c4 + 3][r] = f2bf(v.w);
    }
    __syncthreads();
    const int n = t >> 2, kc = (t & 3) * 16;
    *(short8*)&Wt[(size_t)(n0 + n) * 1024 + k0 + kc]     = *(const short8*)&Ls[n][kc];
    *(short8*)&Wt[(size_t)(n0 + n) * 1024 + k0 + kc + 8] = *(const short8*)&Ls[n][kc + 8];
}

// ---------------------------------------------------------------------------
// bf16 MFMA GEMM body (m97 structure): C = A[M][1024] @ Bt[1024][1024]^T.
// 128x128 tile, BK=32, 4 waves, global_load_lds(16B). N=K=1024 hardcoded.
// ---------------------------------------------------------------------------
template <bool OUTF32>
static __device__ __forceinline__ void gemm_body(
    const ushort* __restrict__ A, const ushort* __restrict__ Bt,
    const float* __restrict__ bias, void* __restrict__ Cout, float osc)
{
    __shared__ ushort As[128 * 32];
    __shared__ ushort Bs[128 * 32];
    const int t = threadIdx.x;
    const int w = t >> 6, l = t & 63, lr = l & 15, lg = l >> 4;
    const int wr = w >> 1, wc = w & 1;
    const int n0 = blockIdx.x * 128, m0 = blockIdx.y * 128;

    const int c0 = t, c1 = t + 256;
    const ushort* a0 = &A[(size_t)(m0 + (c0 >> 2)) * 1024 + (c0 & 3) * 8];
    const ushort* a1 = &A[(size_t)(m0 + (c1 >> 2)) * 1024 + (c1 & 3) * 8];
    const ushort* b0 = &Bt[(size_t)(n0 + (c0 >> 2)) * 1024 + (c0 & 3) * 8];
    const ushort* b1 = &Bt[(size_t)(n0 + (c1 >> 2)) * 1024 + (c1 & 3) * 8];
    ushort* lA0 = &As[w * 512];
    ushort* lA1 = &As[(4 + w) * 512];
    ushort* lB0 = &Bs[w * 512];
    ushort* lB1 = &Bs[(4 + w) * 512];

    f32x4 acc[4][4];
    #pragma unroll
    for (int i = 0; i < 4; ++i)
        #pragma unroll
        for (int j = 0; j < 4; ++j) acc[i][j] = 0.f;

    for (int k0 = 0; k0 < 1024; k0 += 32) {
        __syncthreads();
        GL16(a0 + k0, lA0);
        GL16(a1 + k0, lA1);
        GL16(b0 + k0, lB0);
        GL16(b1 + k0, lB1);
        __syncthreads();
        short8 af[4], bf[4];
        #pragma unroll
        for (int mi = 0; mi < 4; ++mi)
            af[mi] = *(const short8*)&As[(wr * 64 + mi * 16 + lr) * 32 + lg * 8];
        #pragma unroll
        for (int nj = 0; nj < 4; ++nj)
            bf[nj] = *(const short8*)&Bs[(wc * 64 + nj * 16 + lr) * 32 + lg * 8];
        #pragma unroll
        for (int mi = 0; mi < 4; ++mi)
            #pragma unroll
            for (int nj = 0; nj < 4; ++nj)
                acc[mi][nj] = __builtin_amdgcn_mfma_f32_16x16x32_bf16(
                    af[mi], bf[nj], acc[mi][nj], 0, 0, 0);
    }

    const int row0 = m0 + wr * 64, col0 = n0 + wc * 64;
    #pragma unroll
    for (int mi = 0; mi < 4; ++mi)
        #pragma unroll
        for (int nj = 0; nj < 4; ++nj) {
            const int col = col0 + nj * 16 + lr;
            #pragma unroll
            for (int r = 0; r < 4; ++r) {
                const int row = row0 + mi * 16 + lg * 4 + r;
                const float v = acc[mi][nj][r];
                if (OUTF32)
                    ((float*)Cout)[(size_t)row * 1024 + col] = v + bias[col];
                else
                    ((ushort*)Cout)[(size_t)row * 1024 + col] = f2bf(v * osc);
            }
        }
}

__global__ __launch_bounds__(256) void gemm_qkv(
    const ushort* __restrict__ Pb, const ushort* __restrict__ Cb,
    const ushort* __restrict__ Wqt, const ushort* __restrict__ Wkt,
    const ushort* __restrict__ Wvt,
    ushort* __restrict__ Qb, ushort* __restrict__ Kb, ushort* __restrict__ Vb)
{
    const int z = blockIdx.z;
    const ushort* A  = (z == 0) ? Pb : Cb;
    const ushort* Bt = (z == 0) ? Wqt : (z == 1) ? Wkt : Wvt;
    ushort* C = (z == 0) ? Qb : (z == 1) ? Kb : Vb;
    const float osc = (z == 0) ? QSC : 1.0f;   // fold softmax scale*log2e into Q
    gemm_body<false>(A, Bt, nullptr, C, osc);
}

__global__ __launch_bounds__(256) void gemm_out(
    const ushort* __restrict__ A, const ushort* __restrict__ Bt,
    const float* __restrict__ bias, float* __restrict__ Cout)
{
    gemm_body<true>(A, Bt, bias, Cout, 1.0f);
}

// ---------------------------------------------------------------------------
// Classify each 64x64 mask tile: 0 = all masked, 1 = all pass, 2 = mixed.
// ---------------------------------------------------------------------------
__global__ __launch_bounds__(256) void mask_classify(
    const int* __restrict__ amask, const int* __restrict__ pmask,
    int* __restrict__ cls)
{
    const int bid = blockIdx.x;
    const int b = bid >> 10, xb = (bid >> 5) & 31, zb = bid & 31;
    const int t = threadIdx.x;
    int andv = 1, orv = 0;
    #pragma unroll
    for (int i = 0; i < 16; ++i) {
        const int e = t + i * 256;
        const int r = e >> 6, z = e & 63;
        const int m = amask[((size_t)b * LX + xb * 64 + r) * LZ + zb * 64 + z];
        const int p = pmask[(size_t)b * LZ + zb * 64 + z];
        const int v = (m != 0) & (p != 0);
        andv &= v; orv |= v;
    }
    __shared__ int sa[256];
    __shared__ int so[256];
    sa[t] = andv; so[t] = orv;
    __syncthreads();
    for (int s = 128; s > 0; s >>= 1) {
        if (t < s) { sa[t] &= sa[t + s]; so[t] |= so[t + s]; }
        __syncthreads();
    }
    if (t == 0) cls[bid] = so[0] ? (sa[0] ? 1 : 2) : 0;
}

// ---------------------------------------------------------------------------
// MFMA flash attention. 64 q-rows/block (4 waves x 16 rows) -> 1024 blocks
// = 4 blocks/CU (occupancy fix). Swapped QK^T; zero-shuffle PV via the
// sigma z-order trick (slot z-order zeta(lg,ks,j) = ks*32+(j>=4)*16+lg*4+(j&3):
// each lane's PV A-frag is its own softmax registers; V-frags read matching
// permuted z-runs as ds_read_b64 from chunk-XOR-swizzled Vt). Defer-max
// (THR=8 base-2); setprio(1) around MFMA clusters. cls is block-uniform:
// fully-masked tiles skip staging entirely.
// ---------------------------------------------------------------------------
__global__ __launch_bounds__(256, 4) void attn_mfma(
    const ushort* __restrict__ Qg, const ushort* __restrict__ Kg,
    const ushort* __restrict__ Vg, const int* __restrict__ amask,
    const int* __restrict__ pmask, const int* __restrict__ cls,
    ushort* __restrict__ O)
{
    __shared__ ushort Ks[64 * 72];   // [z][d], pad 72
    __shared__ ushort Vt[64 * 64];   // [m][z], chunk-XOR swizzled

    const int t = threadIdx.x, w = t >> 6, l = t & 63, lr = l & 15, lg = l >> 4;
    const int x = blockIdx.x, h = blockIdx.y, b = blockIdx.z;
    // load-balance remap: pairs (2c,2c+1) and (c,c+256) both sum to const work
    const int fx = (x & 1) ? 31 - (x >> 1) : (x >> 1);
    const int qb = b ? 31 - fx : fx;
    const int qw = qb * 64 + w * 16;

    // Q B-frags: lane holds Q[q = lr][d = ks*32 + lg*8 .. +8]
    short8 qf[2];
    #pragma unroll
    for (int ks = 0; ks < 2; ++ks)
        qf[ks] = *(const short8*)&Qg[(size_t)(b * LX + qw + lr) * HD
                                     + h * DA + ks * 32 + lg * 8];

    float mrun = -1e30f, lrun = 0.f;
    f32x4 o[4];
    #pragma unroll
    for (int mj = 0; mj < 4; ++mj) o[mj] = 0.f;

    const int kz = t >> 2, kc = (t & 3) * 16;      // K staging
    const int vz = (t >> 3) * 2, vc = (t & 7) * 8; // V staging (2 rows x 8 cols)

    for (int zb = 0; zb < LZ / 64; ++zb) {
        const int cl = cls[b * 1024 + qb * 32 + zb];   // uniform across block
        if (cl == 0) continue;
        const int z0 = zb * 64;

        __syncthreads();                // prior tile's LDS reads done
        {
            const ushort* kp = &Kg[(size_t)(b * LZ + z0 + kz) * HD + h * DA + kc];
            *(short8*)&Ks[kz * 72 + kc]     = *(const short8*)kp;
            *(short8*)&Ks[kz * 72 + kc + 8] = *(const short8*)(kp + 8);
            const ushort* vp = &Vg[(size_t)(b * LZ + z0 + vz) * HD + h * DM + vc];
            short8 v0 = *(const short8*)vp;
            short8 v1 = *(const short8*)(vp + HD);
            const int zc = vz >> 3, zo = vz & 7;
            #pragma unroll
            for (int j = 0; j < 8; ++j) {
                const int m = vc + j;
                const int idx = m * 64 + (((zc ^ m ^ (m >> 3)) & 7) << 3) + zo;
                const uint32_t pr = (uint32_t)(ushort)v0[j] | ((uint32_t)(ushort)v1[j] << 16);
                *(uint32_t*)&Vt[idx] = pr;
            }
        }
        __syncthreads();

        // ---- S^T = K @ Q : lane holds S[q=lr][z = nj*16 + lg*4 + r] ----
        f32x4 s[4];
        __builtin_amdgcn_s_setprio(1);
        #pragma unroll
        for (int nj = 0; nj < 4; ++nj) {
            const short8 kf0 = *(const short8*)&Ks[(nj * 16 + lr) * 72 + lg * 8];
            const short8 kf1 = *(const short8*)&Ks[(nj * 16 + lr) * 72 + 32 + lg * 8];
            f32x4 z4 = 0.f;
            z4 = __builtin_amdgcn_mfma_f32_16x16x32_bf16(kf0, qf[0], z4, 0, 0, 0);
            z4 = __builtin_amdgcn_mfma_f32_16x16x32_bf16(kf1, qf[1], z4, 0, 0, 0);
            s[nj] = z4;
        }
        __builtin_amdgcn_s_setprio(0);
        // ---- mask (mixed tiles only) ----
        if (cl == 2) {
            const size_t arow = (size_t)(b * LX + qw + lr) * LZ + z0;
            #pragma unroll
            for (int nj = 0; nj < 4; ++nj)
                #pragma unroll
                for (int r = 0; r < 4; ++r) {
                    const int z = nj * 16 + lg * 4 + r;
                    const int ok = (amask[arow + z] != 0) & (pmask[b * LZ + z0 + z] != 0);
                    if (!ok) s[nj][r] = MINF;
                }
        }
        // ---- online softmax, base-2, defer-max (row stats live at q=lr) ----
        {
            float pm = s[0][0];
            #pragma unroll
            for (int nj = 0; nj < 4; ++nj)
                #pragma unroll
                for (int r = 0; r < 4; ++r) pm = fmaxf(pm, s[nj][r]);
            pm = fmaxf(pm, __shfl_xor(pm, 16));
            pm = fmaxf(pm, __shfl_xor(pm, 32));
            if (__any(pm > mrun + DTHR)) {
                const float mn = fmaxf(mrun, pm);
                const float al = exp2f(mrun - mn);
                mrun = mn;
                lrun *= al;
                #pragma unroll
                for (int r = 0; r < 4; ++r) {
                    const float alq = __shfl(al, (lg << 2) + r);
                    #pragma unroll
                    for (int mj = 0; mj < 4; ++mj) o[mj][r] *= alq;
                }
            }
            float sum = 0.f;
            #pragma unroll
            for (int nj = 0; nj < 4; ++nj)
                #pragma unroll
                for (int r = 0; r < 4; ++r) {
                    const float p = exp2f(s[nj][r] - mrun);
                    s[nj][r] = p;
                    sum += p;
                }
            sum += __shfl_xor(sum, 16);
            sum += __shfl_xor(sum, 32);
            lrun += sum;
        }
        // ---- P -> PV A-frags: pack own registers (sigma z-order) ----
        short8 pa[2];
        {
            uint32_t pk01[4], pk23[4];
            #pragma unroll
            for (int nj = 0; nj < 4; ++nj) {
                pk01[nj] = cvtpk(s[nj][0], s[nj][1]);
                pk23[nj] = cvtpk(s[nj][2], s[nj][3]);
            }
            #pragma unroll
            for (int ks = 0; ks < 2; ++ks) {
                union { uint32_t d[4]; short8 v; } u;
                u.d[0] = pk01[2 * ks];
                u.d[1] = pk23[2 * ks];
                u.d[2] = pk01[2 * ks + 1];
                u.d[3] = pk23[2 * ks + 1];
                pa[ks] = u.v;
            }
        }
        // ---- O += P @ V (V-frags in matching sigma z-order, 4x b64 each) ----
        __builtin_amdgcn_s_setprio(1);
        #pragma unroll
        for (int mj = 0; mj < 4; ++mj) {
            const int m_ = mj * 16 + lr;
            const int xr = (m_ ^ (m_ >> 3)) & 7;
            const int czb = lg >> 1;             // (lg*4)>>3
            const int zo = (lg & 1) * 4;
            #pragma unroll
            for (int ks = 0; ks < 2; ++ks) {
                const int clo = (ks * 4 + czb) ^ xr;
                const int chi = (ks * 4 + 2 + czb) ^ xr;
                const uint2 lo = *(const uint2*)&Vt[m_ * 64 + ((clo & 7) << 3) + zo];
                const uint2 hi = *(const uint2*)&Vt[m_ * 64 + ((chi & 7) << 3) + zo];
                union { uint32_t d[4]; short8 v; } u;
                u.d[0] = lo.x; u.d[1] = lo.y; u.d[2] = hi.x; u.d[3] = hi.y;
                o[mj] = __builtin_amdgcn_mfma_f32_16x16x32_bf16(pa[ks], u.v, o[mj], 0, 0, 0);
            }
        }
        __builtin_amdgcn_s_setprio(0);
    }

    // ---- normalize + store (l lives at q=lr; O rows are q=lg*4+r -> shfl) ----
    const float linv = 1.f / lrun;
    #pragma unroll
    for (int r = 0; r < 4; ++r) {
        const float iq = __shfl(linv, (lg << 2) + r);
        #pragma unroll
        for (int mj = 0; mj < 4; ++mj)
            O[(size_t)(b * LX + qw + (lg << 2) + r) * HD + h * DM + mj * 16 + lr]
                = f2bf(o[mj][r] * iq);
    }
}

// ---------------------------------------------------------------------------
extern "C" void kernel_launch(void* const* d_in, const int* in_sizes, int n_in,
                              void* d_out, int out_size, void* d_ws, size_t ws_size,
                              hipStream_t stream)
{
    const float* primary = (const float*)d_in[0];
    const float* context = (const float*)d_in[1];
    const int*   pmask   = (const int*)d_in[2];
    const int*   amask   = (const int*)d_in[3];
    const float* Wq      = (const float*)d_in[4];
    const float* Wk      = (const float*)d_in[5];
    const float* Wv      = (const float*)d_in[6];
    const float* Wo      = (const float*)d_in[7];
    const float* bo      = (const float*)d_in[8];
    float* out = (float*)d_out;

    char* w8 = (char*)d_ws;
    ushort* Pb  = (ushort*)(w8 + 0);
    ushort* Cb  = (ushort*)(w8 + 8388608);
    ushort* Qb  = (ushort*)(w8 + 16777216);
    ushort* Kb  = (ushort*)(w8 + 25165824);
    ushort* Vb  = (ushort*)(w8 + 33554432);
    ushort* AOb = (ushort*)(w8 + 41943040);
    ushort* Wqt = (ushort*)(w8 + 50331648);
    ushort* Wkt = (ushort*)(w8 + 52428800);
    ushort* Wvt = (ushort*)(w8 + 54525952);
    ushort* Wot = (ushort*)(w8 + 56623104);
    int*    clsp = (int*)(w8 + 58720256);

    cvt_both<<<8192, 256, 0, stream>>>(primary, context, Pb, Cb);
    wtrans4<<<dim3(16, 16, 4), 256, 0, stream>>>(Wq, Wk, Wv, Wo, Wqt, Wkt, Wvt, Wot);
    mask_classify<<<NB * 32 * 32, 256, 0, stream>>>(amask, pmask, clsp);
    gemm_qkv<<<dim3(8, 32, 3), 256, 0, stream>>>(Pb, Cb, Wqt, Wkt, Wvt, Qb, Kb, Vb);
    attn_mfma<<<dim3(32, 16, 2), 256, 0, stream>>>(Qb, Kb, Vb, amask, pmask, clsp, AOb);
    gemm_out<<<dim3(8, 32), 256, 0, stream>>>(AOb, Wot, bo, out);
}